// Round 4
// baseline (65.459 us; speedup 1.0000x reference)
//
#include <hip/hip_runtime.h>
#include <hip/hip_bf16.h>

// HeadUpdator: fused bilinear-upsample+sigmoid+einsum (MFMA) + per-row gating MLP.
// feat (8,64,256,256) f32, head (8,80,64,1) f32, pred (8,80,128,128) f32
// -> out (8,80,64,1,1) f32.

using bf16x8 = __attribute__((ext_vector_type(8))) short;
using f32x4  = __attribute__((ext_vector_type(4))) float;

__device__ __forceinline__ unsigned pk2(float lo, float hi) {
  union { __hip_bfloat162 h2; unsigned u; } cv;
  cv.h2 = __float22bfloat162_rn(make_float2(lo, hi));
  return cv.u;
}
// sigmoid(0.25a + 0.75b), -log2e folded into the lerp weights
__device__ __forceinline__ float sigAB(float a, float b) {
  return __builtin_amdgcn_rcpf(1.0f + __builtin_amdgcn_exp2f(-0.36067376f * a - 1.08202128f * b));
}
// sigmoid(0.75a + 0.25b)
__device__ __forceinline__ float sigBA(float a, float b) {
  return __builtin_amdgcn_rcpf(1.0f + __builtin_amdgcn_exp2f(-1.08202128f * a - 0.36067376f * b));
}

// ---------------- Kernel 1: assemble partials ----------------
// ROWS=2: grid 8*128 blocks (3/CU resident), ROWS=4: grid 8*64. 256 thr, 4 waves.
// Per row: [pred loads -> v-lerp regs] ; [f-batch 16 dwordx4 issued, stays in
// flight]; [h-lerp+sigmoid -> Pfrag (LDS, MFMA-frag order)]; raw barrier
// (lgkm only, NO vmcnt drain); [cvt f + 40 MFMA]; raw barrier.
// In-order vmcnt: pred issued BEFORE f, so pred waits never drain the f-batch.
template<int ROWS>
__global__ __launch_bounds__(256, 3) void k_assemble(
    const float* __restrict__ feat, const float* __restrict__ pred,
    float* __restrict__ partial) {
  __shared__ __align__(16) unsigned short Pfrag[40 * 64 * 8];  // 40 KB

  constexpr int LOGN = (ROWS == 2) ? 7 : 6;   // npart = 256/ROWS
  const int tid = threadIdx.x;
  const int b  = blockIdx.x >> LOGN;
  const int rb = blockIdx.x & ((1 << LOGN) - 1);
  const int wid = tid >> 6, l = tid & 63;
  const int ch16 = l & 15, kg = l >> 4;
  const int c0 = wid << 4;
  const int h0 = rb * ROWS;
  const int gg = tid & 31, nb = tid >> 5;

  f32x4 acc[5] = {};
  const float* fwave = feat + (((size_t)(b * 64 + c0 + ch16)) << 16);
  const float* pbat  = pred + (((size_t)(b * 80)) << 14);

  #pragma unroll
  for (int r = 0; r < ROWS; ++r) {
    const int h = h0 + r;
    const int j = h >> 1;
    int r0, r1; float wy0, wy1;
    if ((h & 1) == 0) { r0 = (j > 0) ? j - 1 : 0; r1 = j; wy0 = 0.25f; wy1 = 0.75f; }
    else              { r0 = j; r1 = (j < 127) ? j + 1 : 127; wy0 = 0.75f; wy1 = 0.25f; }

    // ---- pred loads (FIRST in vmem queue) + v-lerp to regs.
    float y[10][4];
    #pragma unroll
    for (int i = 0; i < 10; ++i) {
      const int n = nb + 8 * i;
      const float* pb = pbat + (((size_t)n) << 14);
      const float4 v0 = *(const float4*)(pb + (r0 << 7) + gg * 4);
      const float4 v1 = *(const float4*)(pb + (r1 << 7) + gg * 4);
      y[i][0] = wy0 * v0.x + wy1 * v1.x; y[i][1] = wy0 * v0.y + wy1 * v1.y;
      y[i][2] = wy0 * v0.z + wy1 * v1.z; y[i][3] = wy0 * v0.w + wy1 * v1.w;
    }

    // ---- f-batch for this row: 16 dwordx4, in flight through sigmoid phase.
    const float* fb = fwave + h * 256;
    float4 f[16];
    #pragma unroll
    for (int ks = 0; ks < 8; ++ks) {
      const int pw = ks * 32 + kg * 8;
      f[2 * ks]     = *(const float4*)(fb + pw);
      f[2 * ks + 1] = *(const float4*)(fb + pw + 4);
    }

    // ---- h-lerp + sigmoid -> Pfrag (hides f latency under VALU).
    #pragma unroll
    for (int i = 0; i < 10; ++i) {
      const int n = nb + 8 * i;
      const float y0 = y[i][0], y1 = y[i][1], y2 = y[i][2], y3 = y[i][3];
      float yl = __shfl_up(y3, 1, 64);   if (gg == 0)  yl = y0;
      float yr = __shfl_down(y0, 1, 64); if (gg == 31) yr = y3;
      float P[8];
      P[0] = sigAB(yl, y0); P[1] = sigBA(y0, y1);
      P[2] = sigAB(y0, y1); P[3] = sigBA(y1, y2);
      P[4] = sigAB(y1, y2); P[5] = sigBA(y2, y3);
      P[6] = sigAB(y2, y3); P[7] = sigBA(y3, yr);
      uint4 s;
      s.x = pk2(P[0], P[1]); s.y = pk2(P[2], P[3]);
      s.z = pk2(P[4], P[5]); s.w = pk2(P[6], P[7]);
      const int ks = gg >> 2, kgw = gg & 3;
      const int slot = kgw * 16 + ((n & 15) ^ ks);
      *(uint4*)&Pfrag[(((ks * 5 + (n >> 4)) * 64) + slot) * 8] = s;
    }
    // raw barrier: lgkm drain only — f-batch stays outstanding in vmcnt.
    asm volatile("s_waitcnt lgkmcnt(0)" ::: "memory");
    __builtin_amdgcn_s_barrier();

    // ---- cvt + MFMA (compiler emits progressive vmcnt waits for f pairs).
    #pragma unroll
    for (int ks = 0; ks < 8; ++ks) {
      const float4 f0 = f[2 * ks], f1 = f[2 * ks + 1];
      union { uint4 u; bf16x8 v; } bu;
      bu.u.x = pk2(f0.x, f0.y); bu.u.y = pk2(f0.z, f0.w);
      bu.u.z = pk2(f1.x, f1.y); bu.u.w = pk2(f1.z, f1.w);
      const int slot = kg * 16 + (ch16 ^ ks);
      #pragma unroll
      for (int m = 0; m < 5; ++m) {
        const bf16x8 af = *(const bf16x8*)&Pfrag[(((ks * 5 + m) * 64) + slot) * 8];
        acc[m] = __builtin_amdgcn_mfma_f32_16x16x32_bf16(af, bu.v, acc[m], 0, 0, 0);
      }
    }
    asm volatile("s_waitcnt lgkmcnt(0)" ::: "memory");
    __builtin_amdgcn_s_barrier();
  }

  // D frag: col = lane&15 (channel), row = (lane>>4)*4 + q (class).
  float* po = partial + ((size_t)((b << LOGN) + rb)) * (80 * 64);
  #pragma unroll
  for (int m = 0; m < 5; ++m) {
    #pragma unroll
    for (int q = 0; q < 4; ++q) {
      const int n = m * 16 + kg * 4 + q;
      po[n * 64 + c0 + ch16] = acc[m][q];
    }
  }
}

// ---------------- Kernel 2: reduce + head-update chain ----------------
__device__ __forceinline__ float wred64(float v) {
  #pragma unroll
  for (int off = 32; off > 0; off >>= 1) v += __shfl_xor(v, off, 64);
  return v;
}
__device__ __forceinline__ float lnorm(float x, const float* __restrict__ g,
                                       const float* __restrict__ be, int l) {
  const float m = wred64(x) * 0.015625f;
  const float d = x - m;
  const float var = wred64(d * d) * 0.015625f;
  return d * rsqrtf(var + 1e-5f) * g[l] + be[l];
}
__device__ __forceinline__ float sigmf(float x) {
  return __builtin_amdgcn_rcpf(1.0f + __builtin_amdgcn_exp2f(-1.44269504f * x));
}

// grid = 640 blocks (one per output row), 256 threads.
// All 4 waves cooperate on the npart-deep partial reduction (coalesced over c,
// quarters over jj); wave 0 then runs the gating/LN chain.
__global__ __launch_bounds__(256) void k_head(
    const float* __restrict__ partial, const float* __restrict__ head,
    const float* __restrict__ Wpt, const float* __restrict__ bpt,
    const float* __restrict__ Wht, const float* __restrict__ bht,
    const float* __restrict__ Wpg, const float* __restrict__ bpg,
    const float* __restrict__ Whg, const float* __restrict__ bhg,
    const float* __restrict__ Wfc, const float* __restrict__ bfc,
    const float* __restrict__ g_pin, const float* __restrict__ be_pin,
    const float* __restrict__ g_hin, const float* __restrict__ be_hin,
    const float* __restrict__ g_pout, const float* __restrict__ be_pout,
    const float* __restrict__ g_hout, const float* __restrict__ be_hout,
    const float* __restrict__ g_fc, const float* __restrict__ be_fc,
    float* __restrict__ out, int npart) {
  __shared__ float red[4][64];
  __shared__ float buf[4][64];   // a, hd, gate, upd
  const int tid = threadIdx.x, c = tid & 63, q = tid >> 6;
  const int r = blockIdx.x;              // [0,640)
  const int b = r / 80, n = r % 80;
  const int npq = npart >> 2;

  const float* pp = partial + ((size_t)b * npart + (size_t)q * npq) * 5120 + n * 64 + c;
  float s = 0.f;
  #pragma unroll 8
  for (int jj = 0; jj < npq; ++jj) s += pp[(size_t)jj * 5120];
  red[q][c] = s;
  __syncthreads();

  if (q == 0) {
    const float a_c = red[0][c] + red[1][c] + red[2][c] + red[3][c];
    buf[0][c] = a_c;
    buf[1][c] = head[(size_t)r * 64 + c];

    float pf_in = bpt[c], pf_out = bpt[64 + c];
    float hf_in = bht[c], hf_out = bht[64 + c];
    #pragma unroll 8
    for (int k = 0; k < 64; ++k) {
      const float av = buf[0][k];
      const float hv = buf[1][k];
      pf_in  += av * Wpt[k * 128 + c];
      pf_out += av * Wpt[k * 128 + 64 + c];
      hf_in  += hv * Wht[k * 128 + c];
      hf_out += hv * Wht[k * 128 + 64 + c];
    }
    buf[2][c] = hf_in * pf_in;

    float hg = bhg[c], pg = bpg[c];
    #pragma unroll 8
    for (int k = 0; k < 64; ++k) {
      const float gv = buf[2][k];
      hg += gv * Whg[k * 64 + c];
      pg += gv * Wpg[k * 64 + c];
    }
    const float head_gate = sigmf(lnorm(hg, g_hin, be_hin, c));
    const float pred_gate = sigmf(lnorm(pg, g_pin, be_pin, c));
    const float hfo = lnorm(hf_out, g_hout, be_hout, c);
    const float pfo = lnorm(pf_out, g_pout, be_pout, c);
    buf[3][c] = pred_gate * pfo + head_gate * hfo;

    float fc = bfc[c];
    #pragma unroll 8
    for (int k = 0; k < 64; ++k)
      fc += buf[3][k] * Wfc[k * 64 + c];
    float o = lnorm(fc, g_fc, be_fc, c);
    out[(size_t)r * 64 + c] = fmaxf(o, 0.f);
  }
}

extern "C" void kernel_launch(void* const* d_in, const int* in_sizes, int n_in,
                              void* d_out, int out_size, void* d_ws, size_t ws_size,
                              hipStream_t stream) {
  const float* feat   = (const float*)d_in[0];
  const float* head   = (const float*)d_in[1];
  const float* pred   = (const float*)d_in[2];
  const float* Wpt    = (const float*)d_in[3];
  const float* bpt    = (const float*)d_in[4];
  const float* Wht    = (const float*)d_in[5];
  const float* bht    = (const float*)d_in[6];
  const float* Wpg    = (const float*)d_in[7];
  const float* bpg    = (const float*)d_in[8];
  const float* Whg    = (const float*)d_in[9];
  const float* bhg    = (const float*)d_in[10];
  const float* Wfc    = (const float*)d_in[11];
  const float* bfc    = (const float*)d_in[12];
  const float* g_pin  = (const float*)d_in[13];
  const float* be_pin = (const float*)d_in[14];
  const float* g_hin  = (const float*)d_in[15];
  const float* be_hin = (const float*)d_in[16];
  const float* g_pout = (const float*)d_in[17];
  const float* be_pout= (const float*)d_in[18];
  const float* g_hout = (const float*)d_in[19];
  const float* be_hout= (const float*)d_in[20];
  const float* g_fc   = (const float*)d_in[21];
  const float* be_fc  = (const float*)d_in[22];
  float* out = (float*)d_out;
  float* partial = (float*)d_ws;

  // npart=128 needs 8*128*5120*4 = 20.97 MB of workspace; else fall back.
  const bool big = ws_size >= (size_t)8 * 128 * 5120 * 4;
  const int npart = big ? 128 : 64;

  if (big)
    hipLaunchKernelGGL((k_assemble<2>), dim3(8 * 128), dim3(256), 0, stream,
                       feat, pred, partial);
  else
    hipLaunchKernelGGL((k_assemble<4>), dim3(8 * 64), dim3(256), 0, stream,
                       feat, pred, partial);

  hipLaunchKernelGGL(k_head, dim3(640), dim3(256), 0, stream,
                     partial, head, Wpt, bpt, Wht, bht, Wpg, bpg, Whg, bhg,
                     Wfc, bfc, g_pin, be_pin, g_hin, be_hin, g_pout, be_pout,
                     g_hout, be_hout, g_fc, be_fc, out, npart);
}

// Round 5
// 64.700 us; speedup vs baseline: 1.0117x; 1.0117x over previous
//
#include <hip/hip_runtime.h>
#include <hip/hip_bf16.h>

// HeadUpdator: fused bilinear-upsample+sigmoid+einsum (MFMA, asm-pipelined
// global loads with counted vmcnt) + per-row gating MLP.
// feat (8,64,256,256) f32, head (8,80,64,1) f32, pred (8,80,128,128) f32
// -> out (8,80,64,1,1) f32.

using bf16x8 = __attribute__((ext_vector_type(8))) short;
using f32x4  = __attribute__((ext_vector_type(4))) float;

#define NPART 64   // row-groups per batch (each block covers 4 output rows)
#define ROWS 4

// ---- asm primitives -------------------------------------------------------
// Issue a 16B global load into dst; stays in the vmcnt queue until waited.
#define GLD4(dst, ptr) \
  asm volatile("global_load_dwordx4 %0, %1, off" : "=v"(dst) : "v"(ptr) : "memory")
// Counted wait + scheduling fence (rule #18: consumers must not hoist past).
#define WAITV(n) do { \
  asm volatile("s_waitcnt vmcnt(" #n ")" ::: "memory"); \
  __builtin_amdgcn_sched_barrier(0); } while (0)
#define LGKM_BARRIER() do { \
  asm volatile("s_waitcnt lgkmcnt(0)" ::: "memory"); \
  __builtin_amdgcn_s_barrier(); } while (0)

__device__ __forceinline__ unsigned pk2(float lo, float hi) {
  union { __hip_bfloat162 h2; unsigned u; } cv;
  cv.h2 = __float22bfloat162_rn(make_float2(lo, hi));
  return cv.u;
}
// sigmoid(0.25a + 0.75b), -log2e folded into the lerp weights
__device__ __forceinline__ float sigAB(float a, float b) {
  return __builtin_amdgcn_rcpf(1.0f + __builtin_amdgcn_exp2f(-0.36067376f * a - 1.08202128f * b));
}
// sigmoid(0.75a + 0.25b)
__device__ __forceinline__ float sigBA(float a, float b) {
  return __builtin_amdgcn_rcpf(1.0f + __builtin_amdgcn_exp2f(-1.08202128f * a - 0.36067376f * b));
}

// One output row: steady-state VMEM queue (FIFO) entering this row is
// [pred(R): 20][feat(R): 16]  (pred issued before feat last iteration).
//  A: vmcnt(16)  -> pred(R) retired, feat(R) still in flight
//  B: lerp+sigmoid -> Pfrag (VALU hides feat latency); lgkm barrier
//  D: issue pred(R+1) (20 loads)
//  E: 8 steps; each: vmcnt(34) retires exactly one feat(R) pair; cvt; issue
//     one feat(R+1) pair; 5 MFMA.  Queue leaves as [pred(R+1)20][feat(R+1)16].
template<int R>
__device__ __forceinline__ void row_body(
    const float* __restrict__ fwave, const float* __restrict__ pbat,
    unsigned short* Pfrag, int h0, int gg, int nb, int ch16, int kg,
    f32x4 (&FCUR)[16], f32x4 (&FNXT)[16],
    f32x4 (&p0)[10], f32x4 (&p1)[10], f32x4 (&acc)[5]) {
  const int h = h0 + R;
  constexpr float wy0 = (R & 1) ? 0.75f : 0.25f;
  constexpr float wy1 = (R & 1) ? 0.25f : 0.75f;

  // ---- A: wait for pred(R) only (feat(R) stays outstanding).
  WAITV(16);

  // ---- B: v-lerp + h-lerp + sigmoid -> Pfrag (MFMA-fragment order).
  #pragma unroll
  for (int i = 0; i < 10; ++i) {
    const int n = nb + 8 * i;
    const float y0 = wy0 * p0[i][0] + wy1 * p1[i][0];
    const float y1 = wy0 * p0[i][1] + wy1 * p1[i][1];
    const float y2 = wy0 * p0[i][2] + wy1 * p1[i][2];
    const float y3 = wy0 * p0[i][3] + wy1 * p1[i][3];
    float yl = __shfl_up(y3, 1, 64);   if (gg == 0)  yl = y0;  // col 4g-1 clamp
    float yr = __shfl_down(y0, 1, 64); if (gg == 31) yr = y3;  // col 4g+4 clamp
    float P[8];
    P[0] = sigAB(yl, y0); P[1] = sigBA(y0, y1);
    P[2] = sigAB(y0, y1); P[3] = sigBA(y1, y2);
    P[4] = sigAB(y1, y2); P[5] = sigBA(y2, y3);
    P[6] = sigAB(y2, y3); P[7] = sigBA(y3, yr);
    uint4 s;
    s.x = pk2(P[0], P[1]); s.y = pk2(P[2], P[3]);
    s.z = pk2(P[4], P[5]); s.w = pk2(P[6], P[7]);
    const int ks = gg >> 2, kgw = gg & 3;
    const int slot = kgw * 16 + ((n & 15) ^ ks);
    *(uint4*)&Pfrag[(((ks * 5 + (n >> 4)) * 64) + slot) * 8] = s;
  }
  LGKM_BARRIER();   // lgkm only — feat(R) stays in the vmcnt queue

  // ---- D: issue pred(R+1) (queue: [feat(R)16][pred(R+1)20]).
  if constexpr (R < ROWS - 1) {
    const int hn = h + 1;
    const int j = hn >> 1;
    int r0_, r1_;
    if ((hn & 1) == 0) { r0_ = (j > 0) ? j - 1 : 0; r1_ = j; }
    else               { r0_ = j; r1_ = (j < 127) ? j + 1 : 127; }
    #pragma unroll
    for (int i = 0; i < 10; ++i) {
      const float* pb = pbat + (((size_t)(nb + 8 * i)) << 14);
      GLD4(p0[i], pb + (r0_ << 7) + gg * 4);
      GLD4(p1[i], pb + (r1_ << 7) + gg * 4);
    }
  }

  // ---- E: MFMA + stream feat(R+1).
  if constexpr (R == ROWS - 1) { WAITV(0); }  // last row: drain remaining feat
  const float* fbn = fwave + (h + 1) * 256;   // computed only; guarded below
  #pragma unroll
  for (int ks = 0; ks < 8; ++ks) {
    if constexpr (R < ROWS - 1) { WAITV(34); }  // retire exactly feat(R) pair ks
    const f32x4 f0 = FCUR[2 * ks], f1 = FCUR[2 * ks + 1];
    union { uint4 u; bf16x8 v; } bu;
    bu.u.x = pk2(f0[0], f0[1]); bu.u.y = pk2(f0[2], f0[3]);
    bu.u.z = pk2(f1[0], f1[1]); bu.u.w = pk2(f1[2], f1[3]);
    if constexpr (R < ROWS - 1) {
      GLD4(FNXT[2 * ks],     fbn + ks * 32 + kg * 8);
      GLD4(FNXT[2 * ks + 1], fbn + ks * 32 + kg * 8 + 4);
    }
    const int slot = kg * 16 + (ch16 ^ ks);
    #pragma unroll
    for (int m = 0; m < 5; ++m) {
      const bf16x8 af = *(const bf16x8*)&Pfrag[(((ks * 5 + m) * 64) + slot) * 8];
      acc[m] = __builtin_amdgcn_mfma_f32_16x16x32_bf16(af, bu.v, acc[m], 0, 0, 0);
    }
  }
  LGKM_BARRIER();   // Pfrag reads done before next row overwrites
}

// ---------------- Kernel 1: assemble partials ----------------
// grid = 8*64 blocks (2/CU resident), 256 threads, LDS 40 KB.
__global__ __launch_bounds__(256, 2) void k_assemble(
    const float* __restrict__ feat, const float* __restrict__ pred,
    float* __restrict__ partial) {
  __shared__ __align__(16) unsigned short Pfrag[40 * 64 * 8];  // 40 KB

  const int tid = threadIdx.x;
  const int b  = blockIdx.x >> 6;
  const int rb = blockIdx.x & 63;
  const int wid = tid >> 6, l = tid & 63;
  const int ch16 = l & 15, kg = l >> 4;
  const int c0 = wid << 4;
  const int h0 = rb * ROWS;
  const int gg = tid & 31, nb = tid >> 5;

  f32x4 acc[5] = {};
  const float* fwave = feat + (((size_t)(b * 64 + c0 + ch16)) << 16);
  const float* pbat  = pred + (((size_t)(b * 80)) << 14);

  f32x4 p0[10], p1[10];
  f32x4 fA[16], fB[16];

  // ---- Prologue: pred(0) then feat(0)  (queue: [pred 20][feat 16]).
  {
    const int j = h0 >> 1;                       // h0 even
    const int r0_ = (j > 0) ? j - 1 : 0, r1_ = j;
    #pragma unroll
    for (int i = 0; i < 10; ++i) {
      const float* pb = pbat + (((size_t)(nb + 8 * i)) << 14);
      GLD4(p0[i], pb + (r0_ << 7) + gg * 4);
      GLD4(p1[i], pb + (r1_ << 7) + gg * 4);
    }
    const float* fb = fwave + h0 * 256;
    #pragma unroll
    for (int ks = 0; ks < 8; ++ks) {
      GLD4(fA[2 * ks],     fb + ks * 32 + kg * 8);
      GLD4(fA[2 * ks + 1], fb + ks * 32 + kg * 8 + 4);
    }
  }

  row_body<0>(fwave, pbat, Pfrag, h0, gg, nb, ch16, kg, fA, fB, p0, p1, acc);
  row_body<1>(fwave, pbat, Pfrag, h0, gg, nb, ch16, kg, fB, fA, p0, p1, acc);
  row_body<2>(fwave, pbat, Pfrag, h0, gg, nb, ch16, kg, fA, fB, p0, p1, acc);
  row_body<3>(fwave, pbat, Pfrag, h0, gg, nb, ch16, kg, fB, fA, p0, p1, acc);

  // D frag: col = lane&15 (channel), row = (lane>>4)*4 + q (class).
  float* po = partial + ((size_t)(b * NPART + rb)) * (80 * 64);
  #pragma unroll
  for (int m = 0; m < 5; ++m) {
    #pragma unroll
    for (int q = 0; q < 4; ++q) {
      const int n = m * 16 + kg * 4 + q;
      po[n * 64 + c0 + ch16] = acc[m][q];
    }
  }
}

// ---------------- Kernel 2: reduce + head-update chain ----------------
__device__ __forceinline__ float wred64(float v) {
  #pragma unroll
  for (int off = 32; off > 0; off >>= 1) v += __shfl_xor(v, off, 64);
  return v;
}
__device__ __forceinline__ float lnorm(float x, const float* __restrict__ g,
                                       const float* __restrict__ be, int l) {
  const float m = wred64(x) * 0.015625f;
  const float d = x - m;
  const float var = wred64(d * d) * 0.015625f;
  return d * rsqrtf(var + 1e-5f) * g[l] + be[l];
}
__device__ __forceinline__ float sigmf(float x) {
  return __builtin_amdgcn_rcpf(1.0f + __builtin_amdgcn_exp2f(-1.44269504f * x));
}

// grid = 640 blocks (one per output row), 256 threads.
__global__ __launch_bounds__(256) void k_head(
    const float* __restrict__ partial, const float* __restrict__ head,
    const float* __restrict__ Wpt, const float* __restrict__ bpt,
    const float* __restrict__ Wht, const float* __restrict__ bht,
    const float* __restrict__ Wpg, const float* __restrict__ bpg,
    const float* __restrict__ Whg, const float* __restrict__ bhg,
    const float* __restrict__ Wfc, const float* __restrict__ bfc,
    const float* __restrict__ g_pin, const float* __restrict__ be_pin,
    const float* __restrict__ g_hin, const float* __restrict__ be_hin,
    const float* __restrict__ g_pout, const float* __restrict__ be_pout,
    const float* __restrict__ g_hout, const float* __restrict__ be_hout,
    const float* __restrict__ g_fc, const float* __restrict__ be_fc,
    float* __restrict__ out, int npart) {
  __shared__ float red[4][64];
  __shared__ float buf[4][64];   // a, hd, gate, upd
  const int tid = threadIdx.x, c = tid & 63, q = tid >> 6;
  const int r = blockIdx.x;              // [0,640)
  const int b = r / 80, n = r % 80;
  const int npq = npart >> 2;

  const float* pp = partial + ((size_t)b * npart + (size_t)q * npq) * 5120 + n * 64 + c;
  float s = 0.f;
  #pragma unroll 8
  for (int jj = 0; jj < npq; ++jj) s += pp[(size_t)jj * 5120];
  red[q][c] = s;
  __syncthreads();

  if (q == 0) {
    const float a_c = red[0][c] + red[1][c] + red[2][c] + red[3][c];
    buf[0][c] = a_c;
    buf[1][c] = head[(size_t)r * 64 + c];

    float pf_in = bpt[c], pf_out = bpt[64 + c];
    float hf_in = bht[c], hf_out = bht[64 + c];
    #pragma unroll 8
    for (int k = 0; k < 64; ++k) {
      const float av = buf[0][k];
      const float hv = buf[1][k];
      pf_in  += av * Wpt[k * 128 + c];
      pf_out += av * Wpt[k * 128 + 64 + c];
      hf_in  += hv * Wht[k * 128 + c];
      hf_out += hv * Wht[k * 128 + 64 + c];
    }
    buf[2][c] = hf_in * pf_in;

    float hg = bhg[c], pg = bpg[c];
    #pragma unroll 8
    for (int k = 0; k < 64; ++k) {
      const float gv = buf[2][k];
      hg += gv * Whg[k * 64 + c];
      pg += gv * Wpg[k * 64 + c];
    }
    const float head_gate = sigmf(lnorm(hg, g_hin, be_hin, c));
    const float pred_gate = sigmf(lnorm(pg, g_pin, be_pin, c));
    const float hfo = lnorm(hf_out, g_hout, be_hout, c);
    const float pfo = lnorm(pf_out, g_pout, be_pout, c);
    buf[3][c] = pred_gate * pfo + head_gate * hfo;

    float fc = bfc[c];
    #pragma unroll 8
    for (int k = 0; k < 64; ++k)
      fc += buf[3][k] * Wfc[k * 64 + c];
    float o = lnorm(fc, g_fc, be_fc, c);
    out[(size_t)r * 64 + c] = fmaxf(o, 0.f);
  }
}

extern "C" void kernel_launch(void* const* d_in, const int* in_sizes, int n_in,
                              void* d_out, int out_size, void* d_ws, size_t ws_size,
                              hipStream_t stream) {
  const float* feat   = (const float*)d_in[0];
  const float* head   = (const float*)d_in[1];
  const float* pred   = (const float*)d_in[2];
  const float* Wpt    = (const float*)d_in[3];
  const float* bpt    = (const float*)d_in[4];
  const float* Wht    = (const float*)d_in[5];
  const float* bht    = (const float*)d_in[6];
  const float* Wpg    = (const float*)d_in[7];
  const float* bpg    = (const float*)d_in[8];
  const float* Whg    = (const float*)d_in[9];
  const float* bhg    = (const float*)d_in[10];
  const float* Wfc    = (const float*)d_in[11];
  const float* bfc    = (const float*)d_in[12];
  const float* g_pin  = (const float*)d_in[13];
  const float* be_pin = (const float*)d_in[14];
  const float* g_hin  = (const float*)d_in[15];
  const float* be_hin = (const float*)d_in[16];
  const float* g_pout = (const float*)d_in[17];
  const float* be_pout= (const float*)d_in[18];
  const float* g_hout = (const float*)d_in[19];
  const float* be_hout= (const float*)d_in[20];
  const float* g_fc   = (const float*)d_in[21];
  const float* be_fc  = (const float*)d_in[22];
  float* out = (float*)d_out;
  float* partial = (float*)d_ws;  // 8*64*5120*4 = 10.5 MB

  hipLaunchKernelGGL(k_assemble, dim3(8 * NPART), dim3(256), 0, stream,
                     feat, pred, partial);
  hipLaunchKernelGGL(k_head, dim3(640), dim3(256), 0, stream,
                     partial, head, Wpt, bpt, Wht, bht, Wpg, bpg, Whg, bhg,
                     Wfc, bfc, g_pin, be_pin, g_hin, be_hin, g_pout, be_pout,
                     g_hout, be_hout, g_fc, be_fc, out, NPART);
}

// Round 7
// 63.069 us; speedup vs baseline: 1.0379x; 1.0259x over previous
//
#include <hip/hip_runtime.h>
#include <hip/hip_bf16.h>
#include <hip/hip_fp16.h>

// HeadUpdator: fused bilinear-upsample+sigmoid+einsum (MFMA) + per-row gating MLP.
// feat (8,64,256,256) f32, head (8,80,64,1) f32, pred (8,80,128,128) f32
// -> out (8,80,64,1,1) f32.
// Round-6 design (resubmitted after infra failure): TLP-first. ROWS=2 per
// block -> grid 1024 -> 4 resident blocks/CU (16 waves/CU); partials stored
// f16 so NPART=128 fits proven ws.

using bf16x8 = __attribute__((ext_vector_type(8))) short;
using f32x4  = __attribute__((ext_vector_type(4))) float;

#define NPART 128   // row-groups per batch (each block covers 2 output rows)
#define ROWS 2

#define LGKM_BARRIER() do { \
  asm volatile("s_waitcnt lgkmcnt(0)" ::: "memory"); \
  __builtin_amdgcn_s_barrier(); } while (0)

__device__ __forceinline__ unsigned pk2(float lo, float hi) {
  union { __hip_bfloat162 h2; unsigned u; } cv;
  cv.h2 = __float22bfloat162_rn(make_float2(lo, hi));
  return cv.u;
}
// sigmoid(0.25a + 0.75b), -log2e folded into the lerp weights
__device__ __forceinline__ float sigAB(float a, float b) {
  return __builtin_amdgcn_rcpf(1.0f + __builtin_amdgcn_exp2f(-0.36067376f * a - 1.08202128f * b));
}
// sigmoid(0.75a + 0.25b)
__device__ __forceinline__ float sigBA(float a, float b) {
  return __builtin_amdgcn_rcpf(1.0f + __builtin_amdgcn_exp2f(-1.08202128f * a - 0.36067376f * b));
}

// ---------------- Kernel 1: assemble partials ----------------
// grid = 8*128 blocks (4/CU resident), 256 threads, LDS 40 KB.
// Block (b, rb) covers output rows h = 2rb, 2rb+1.
// Per row: [pred loads -> v-lerp regs]; [feat batch issued];
// [h-lerp+sigmoid -> Pfrag]; lgkm barrier; [cvt + 40 MFMA]; lgkm barrier.
// Pfrag layout: fragment F = ks*5+m at bytes [F*1024); lane slot =
// kg*16 + (ch16 ^ ks), 16B/slot.
__global__ __launch_bounds__(256) void k_assemble(
    const float* __restrict__ feat, const float* __restrict__ pred,
    __half* __restrict__ partial) {
  __shared__ __align__(16) unsigned short Pfrag[40 * 64 * 8];  // 40 KB

  const int tid = threadIdx.x;
  const int b  = blockIdx.x >> 7;
  const int rb = blockIdx.x & 127;
  const int wid = tid >> 6, l = tid & 63;
  const int ch16 = l & 15, kg = l >> 4;
  const int c0 = wid << 4;
  const int h0 = rb * ROWS;
  const int gg = tid & 31, nb = tid >> 5;

  f32x4 acc[5] = {};
  const float* fwave = feat + (((size_t)(b * 64 + c0 + ch16)) << 16);
  const float* pbat  = pred + (((size_t)(b * 80)) << 14);

  #pragma unroll
  for (int r = 0; r < ROWS; ++r) {
    const int h = h0 + r;
    const int j = h >> 1;
    int r0, r1; float wy0, wy1;
    if ((h & 1) == 0) { r0 = (j > 0) ? j - 1 : 0; r1 = j; wy0 = 0.25f; wy1 = 0.75f; }
    else              { r0 = j; r1 = (j < 127) ? j + 1 : 127; wy0 = 0.75f; wy1 = 0.25f; }

    // ---- pred loads (first in queue) + v-lerp to regs.
    float y[10][4];
    #pragma unroll
    for (int i = 0; i < 10; ++i) {
      const int n = nb + 8 * i;
      const float* pb = pbat + (((size_t)n) << 14);
      const float4 v0 = *(const float4*)(pb + (r0 << 7) + gg * 4);
      const float4 v1 = *(const float4*)(pb + (r1 << 7) + gg * 4);
      y[i][0] = wy0 * v0.x + wy1 * v1.x; y[i][1] = wy0 * v0.y + wy1 * v1.y;
      y[i][2] = wy0 * v0.z + wy1 * v1.z; y[i][3] = wy0 * v0.w + wy1 * v1.w;
    }

    // ---- feat batch for this row (issued before sigmoid VALU phase).
    const float* fb = fwave + h * 256;
    float4 f[16];
    #pragma unroll
    for (int ks = 0; ks < 8; ++ks) {
      const int pw = ks * 32 + kg * 8;
      f[2 * ks]     = *(const float4*)(fb + pw);
      f[2 * ks + 1] = *(const float4*)(fb + pw + 4);
    }

    // ---- h-lerp + sigmoid -> Pfrag (hides feat latency under VALU).
    #pragma unroll
    for (int i = 0; i < 10; ++i) {
      const int n = nb + 8 * i;
      const float y0 = y[i][0], y1 = y[i][1], y2 = y[i][2], y3 = y[i][3];
      float yl = __shfl_up(y3, 1, 64);   if (gg == 0)  yl = y0;   // col 4g-1 clamp
      float yr = __shfl_down(y0, 1, 64); if (gg == 31) yr = y3;   // col 4g+4 clamp
      float P[8];
      P[0] = sigAB(yl, y0); P[1] = sigBA(y0, y1);
      P[2] = sigAB(y0, y1); P[3] = sigBA(y1, y2);
      P[4] = sigAB(y1, y2); P[5] = sigBA(y2, y3);
      P[6] = sigAB(y2, y3); P[7] = sigBA(y3, yr);
      uint4 s;
      s.x = pk2(P[0], P[1]); s.y = pk2(P[2], P[3]);
      s.z = pk2(P[4], P[5]); s.w = pk2(P[6], P[7]);
      const int ks = gg >> 2, kgw = gg & 3;
      const int slot = kgw * 16 + ((n & 15) ^ ks);
      *(uint4*)&Pfrag[(((ks * 5 + (n >> 4)) * 64) + slot) * 8] = s;
    }
    LGKM_BARRIER();   // lgkm only — feat batch stays in the vmcnt queue

    // ---- cvt + MFMA (compiler inserts progressive vmcnt waits for f).
    #pragma unroll
    for (int ks = 0; ks < 8; ++ks) {
      const float4 f0 = f[2 * ks], f1 = f[2 * ks + 1];
      union { uint4 u; bf16x8 v; } bu;
      bu.u.x = pk2(f0.x, f0.y); bu.u.y = pk2(f0.z, f0.w);
      bu.u.z = pk2(f1.x, f1.y); bu.u.w = pk2(f1.z, f1.w);
      const int slot = kg * 16 + (ch16 ^ ks);
      #pragma unroll
      for (int m = 0; m < 5; ++m) {
        const bf16x8 af = *(const bf16x8*)&Pfrag[(((ks * 5 + m) * 64) + slot) * 8];
        acc[m] = __builtin_amdgcn_mfma_f32_16x16x32_bf16(af, bu.v, acc[m], 0, 0, 0);
      }
    }
    LGKM_BARRIER();   // Pfrag reads done before next row overwrites
  }

  // D frag: col = lane&15 (channel), row = (lane>>4)*4 + q (class).
  __half* po = partial + ((size_t)(b * NPART + rb)) * (80 * 64);
  #pragma unroll
  for (int m = 0; m < 5; ++m) {
    #pragma unroll
    for (int q = 0; q < 4; ++q) {
      const int n = m * 16 + kg * 4 + q;
      po[n * 64 + c0 + ch16] = __float2half(acc[m][q]);
    }
  }
}

// ---------------- Kernel 2: reduce + head-update chain ----------------
__device__ __forceinline__ float wred64(float v) {
  #pragma unroll
  for (int off = 32; off > 0; off >>= 1) v += __shfl_xor(v, off, 64);
  return v;
}
__device__ __forceinline__ float lnorm(float x, const float* __restrict__ g,
                                       const float* __restrict__ be, int l) {
  const float m = wred64(x) * 0.015625f;
  const float d = x - m;
  const float var = wred64(d * d) * 0.015625f;
  return d * rsqrtf(var + 1e-5f) * g[l] + be[l];
}
__device__ __forceinline__ float sigmf(float x) {
  return __builtin_amdgcn_rcpf(1.0f + __builtin_amdgcn_exp2f(-1.44269504f * x));
}

// grid = 640 blocks (one per output row), 256 threads.
// 4 waves cooperate on the npart-deep f16 partial reduction; wave 0 runs the
// gating/LN chain.
__global__ __launch_bounds__(256) void k_head(
    const __half* __restrict__ partial, const float* __restrict__ head,
    const float* __restrict__ Wpt, const float* __restrict__ bpt,
    const float* __restrict__ Wht, const float* __restrict__ bht,
    const float* __restrict__ Wpg, const float* __restrict__ bpg,
    const float* __restrict__ Whg, const float* __restrict__ bhg,
    const float* __restrict__ Wfc, const float* __restrict__ bfc,
    const float* __restrict__ g_pin, const float* __restrict__ be_pin,
    const float* __restrict__ g_hin, const float* __restrict__ be_hin,
    const float* __restrict__ g_pout, const float* __restrict__ be_pout,
    const float* __restrict__ g_hout, const float* __restrict__ be_hout,
    const float* __restrict__ g_fc, const float* __restrict__ be_fc,
    float* __restrict__ out, int npart) {
  __shared__ float red[4][64];
  __shared__ float buf[4][64];   // a, hd, gate, upd
  const int tid = threadIdx.x, c = tid & 63, q = tid >> 6;
  const int r = blockIdx.x;              // [0,640)
  const int b = r / 80, n = r % 80;
  const int npq = npart >> 2;

  const __half* pp = partial + ((size_t)b * npart + (size_t)q * npq) * 5120 + n * 64 + c;
  float s = 0.f;
  #pragma unroll 8
  for (int jj = 0; jj < npq; ++jj) s += __half2float(pp[(size_t)jj * 5120]);
  red[q][c] = s;
  __syncthreads();

  if (q == 0) {
    const float a_c = red[0][c] + red[1][c] + red[2][c] + red[3][c];
    buf[0][c] = a_c;
    buf[1][c] = head[(size_t)r * 64 + c];

    float pf_in = bpt[c], pf_out = bpt[64 + c];
    float hf_in = bht[c], hf_out = bht[64 + c];
    #pragma unroll 8
    for (int k = 0; k < 64; ++k) {
      const float av = buf[0][k];
      const float hv = buf[1][k];
      pf_in  += av * Wpt[k * 128 + c];
      pf_out += av * Wpt[k * 128 + 64 + c];
      hf_in  += hv * Wht[k * 128 + c];
      hf_out += hv * Wht[k * 128 + 64 + c];
    }
    buf[2][c] = hf_in * pf_in;

    float hg = bhg[c], pg = bpg[c];
    #pragma unroll 8
    for (int k = 0; k < 64; ++k) {
      const float gv = buf[2][k];
      hg += gv * Whg[k * 64 + c];
      pg += gv * Wpg[k * 64 + c];
    }
    const float head_gate = sigmf(lnorm(hg, g_hin, be_hin, c));
    const float pred_gate = sigmf(lnorm(pg, g_pin, be_pin, c));
    const float hfo = lnorm(hf_out, g_hout, be_hout, c);
    const float pfo = lnorm(pf_out, g_pout, be_pout, c);
    buf[3][c] = pred_gate * pfo + head_gate * hfo;

    float fc = bfc[c];
    #pragma unroll 8
    for (int k = 0; k < 64; ++k)
      fc += buf[3][k] * Wfc[k * 64 + c];
    float o = lnorm(fc, g_fc, be_fc, c);
    out[(size_t)r * 64 + c] = fmaxf(o, 0.f);
  }
}

extern "C" void kernel_launch(void* const* d_in, const int* in_sizes, int n_in,
                              void* d_out, int out_size, void* d_ws, size_t ws_size,
                              hipStream_t stream) {
  const float* feat   = (const float*)d_in[0];
  const float* head   = (const float*)d_in[1];
  const float* pred   = (const float*)d_in[2];
  const float* Wpt    = (const float*)d_in[3];
  const float* bpt    = (const float*)d_in[4];
  const float* Wht    = (const float*)d_in[5];
  const float* bht    = (const float*)d_in[6];
  const float* Wpg    = (const float*)d_in[7];
  const float* bpg    = (const float*)d_in[8];
  const float* Whg    = (const float*)d_in[9];
  const float* bhg    = (const float*)d_in[10];
  const float* Wfc    = (const float*)d_in[11];
  const float* bfc    = (const float*)d_in[12];
  const float* g_pin  = (const float*)d_in[13];
  const float* be_pin = (const float*)d_in[14];
  const float* g_hin  = (const float*)d_in[15];
  const float* be_hin = (const float*)d_in[16];
  const float* g_pout = (const float*)d_in[17];
  const float* be_pout= (const float*)d_in[18];
  const float* g_hout = (const float*)d_in[19];
  const float* be_hout= (const float*)d_in[20];
  const float* g_fc   = (const float*)d_in[21];
  const float* be_fc  = (const float*)d_in[22];
  float* out = (float*)d_out;
  __half* partial = (__half*)d_ws;  // 8*128*5120*2 = 10.0 MiB (ws proven >= this)

  hipLaunchKernelGGL(k_assemble, dim3(8 * NPART), dim3(256), 0, stream,
                     feat, pred, partial);
  hipLaunchKernelGGL(k_head, dim3(640), dim3(256), 0, stream,
                     partial, head, Wpt, bpt, Wht, bht, Wpg, bpg, Whg, bhg,
                     Wfc, bfc, g_pin, be_pin, g_hin, be_hin, g_pout, be_pout,
                     g_hout, be_hout, g_fc, be_fc, out, NPART);
}